// Round 4
// baseline (1311.276 us; speedup 1.0000x reference)
//
#include <hip/hip_runtime.h>

#define Bq 2
#define Lq 1024
#define Dq 128
#define Vq 5
#define RQ 128   // l1 rows per k_m block

typedef __attribute__((ext_vector_type(4))) float float4v;

// ws layout (floats): [0,640) P1b  [640,1280) P2  [1280] x-dtype flag (int)
#define WS_FLAG_OFF 1280

// ---------------------------------------------------------------------------
// Kernel 0: x dtype insurance. int64 x -> odd int32 words all zero -> flag 0.
// int32 x -> odd words are random 0..4 -> flag nonzero w.p. 1 - 5^-1024.
// ---------------------------------------------------------------------------
__global__ void k_flag(const int* __restrict__ x32, int* __restrict__ flag) {
    __shared__ int red[256];
    const int t = threadIdx.x;
    int acc = 0;
    for (int k = t; k < 1024; k += 256)
        acc |= x32[2 * k + 1];
    red[t] = acc;
    __syncthreads();
    for (int s = 128; s > 0; s >>= 1) {
        if (t < s) red[t] |= red[t + s];
        __syncthreads();
    }
    if (t == 0) flag[0] = red[0];
}

__device__ __forceinline__ int x_at(const int* __restrict__ x32, int f, int idx) {
    return x32[f ? idx : 2 * idx];   // f!=0: int32; f==0: int64 low word
}

// ---------------------------------------------------------------------------
// Kernel 1: blocks [0,5)   -> P1b[v][e] = sum_d emb[v,d]*W[e,d] + bias[e]
//                             P2 [v][e] = sum_d emb[v,d]*W[e,D+d]
//           blocks [5,133) -> s gather (fp32): s[b,l,:] = emb[x[b,l],:]
// All float inputs are fp32; output buffer is fp32.
// ---------------------------------------------------------------------------
__global__ void k_prep(const int* __restrict__ x32,
                       const float* __restrict__ emb,
                       const float* __restrict__ W,
                       const float* __restrict__ bias,
                       float* __restrict__ ws,
                       float* __restrict__ s_out) {
    const int bid = blockIdx.x;
    const int t   = threadIdx.x;
    if (bid < Vq) {
        const int v     = bid;
        const int which = t >> 7;     // 0 -> P1 (+bias), 1 -> P2
        const int e     = t & 127;
        float acc = which ? 0.0f : bias[e];
        const float* wrow = W + e * (2 * Dq) + which * Dq;
        const float* erow = emb + v * Dq;
        #pragma unroll 8
        for (int d = 0; d < Dq; ++d)
            acc += erow[d] * wrow[d];
        ws[which * (Vq * Dq) + v * Dq + e] = acc;
    } else {
        const int f    = ((const int*)ws)[WS_FLAG_OFF];
        const int sb   = bid - Vq;            // 0..127
        const int pair = t >> 4;              // 0..15
        const int dgrp = t & 15;              // 0..15
        const int bl   = sb * 16 + pair;      // flat (b,l), 0..2047
        const int v    = x_at(x32, f, bl);
        const float* src = emb + v * Dq + dgrp * 8;
        float*       dst = s_out + (size_t)bl * Dq + dgrp * 8;
        float4v a = *reinterpret_cast<const float4v*>(src);
        float4v b = *reinterpret_cast<const float4v*>(src + 4);
        *reinterpret_cast<float4v*>(dst)     = a;
        *reinterpret_cast<float4v*>(dst + 4) = b;
    }
}

// ---------------------------------------------------------------------------
// Kernel 2: m[b,e,l1,l2] = P1b[x[b,l1],e] + P2[x[b,l2],e], fp32 out.
// grid = B*D*(L/RQ) = 2048 blocks, 256 threads.
// Thread (r=t>>7, c=t&127): l2 = c*8..c*8+7, rows i = r, r+2, ...
// ---------------------------------------------------------------------------
__global__ void __launch_bounds__(256) k_m(const int* __restrict__ x32,
                                           const float* __restrict__ ws,
                                           float* __restrict__ m_out) {
    constexpr int CH = Lq / RQ;            // 8 chunks
    const int bid   = blockIdx.x;
    const int chunk = bid % CH;
    const int tmp   = bid / CH;
    const int e     = tmp % Dq;
    const int b     = tmp / Dq;
    const int t     = threadIdx.x;
    const int r     = t >> 7;              // 0..1
    const int c     = t & 127;             // 0..127
    const int l1_0  = chunk * RQ;
    const int f     = ((const int*)ws)[WS_FLAG_OFF];

    // P columns for this e (broadcast loads, L2-hit)
    float p1c[Vq], p2c[Vq];
    #pragma unroll
    for (int v = 0; v < Vq; ++v) {
        p1c[v] = ws[v * Dq + e];
        p2c[v] = ws[Vq * Dq + v * Dq + e];
    }

    // per-thread c2[8] for its 8 l2 positions
    const int xbase = b * Lq;
    float c2[8];
    #pragma unroll
    for (int j = 0; j < 8; ++j) {
        const int v = x_at(x32, f, xbase + c * 8 + j);
        float p = p2c[4];
        p = (v == 3) ? p2c[3] : p;
        p = (v == 2) ? p2c[2] : p;
        p = (v == 1) ? p2c[1] : p;
        p = (v == 0) ? p2c[0] : p;
        c2[j] = p;
    }

    // c1 for this block's 128 l1 rows, staged in LDS
    __shared__ float c1s[RQ];
    if (t < RQ) {
        const int v = x_at(x32, f, xbase + l1_0 + t);
        float p = p1c[4];
        p = (v == 3) ? p1c[3] : p;
        p = (v == 2) ? p1c[2] : p;
        p = (v == 1) ? p1c[1] : p;
        p = (v == 0) ? p1c[0] : p;
        c1s[t] = p;
    }
    __syncthreads();

    float* out_base = m_out
        + ((size_t)(b * Dq + e) * Lq + l1_0) * Lq + c * 8;

    #pragma unroll 4
    for (int i = r; i < RQ; i += 2) {
        const float c1 = c1s[i];           // wave-uniform broadcast
        float4v o0, o1;
        #pragma unroll
        for (int j = 0; j < 4; ++j) o0[j] = c1 + c2[j];
        #pragma unroll
        for (int j = 0; j < 4; ++j) o1[j] = c1 + c2[4 + j];
        float* dst = out_base + (size_t)i * Lq;
        __builtin_nontemporal_store(o0, reinterpret_cast<float4v*>(dst));
        __builtin_nontemporal_store(o1, reinterpret_cast<float4v*>(dst + 4));
    }
}

extern "C" void kernel_launch(void* const* d_in, const int* in_sizes, int n_in,
                              void* d_out, int out_size, void* d_ws, size_t ws_size,
                              hipStream_t stream) {
    const int*   x32  = (const int*)d_in[0];    // int32 (int64 auto-handled)
    const float* emb  = (const float*)d_in[1];
    const float* W    = (const float*)d_in[2];
    const float* bias = (const float*)d_in[3];
    float* out   = (float*)d_out;               // fp32 output buffer
    float* ws    = (float*)d_ws;
    float* s_out = out;
    float* m_out = out + (size_t)Bq * Lq * Dq;

    k_flag<<<1, 256, 0, stream>>>(x32, ((int*)ws) + WS_FLAG_OFF);
    k_prep<<<Vq + (Bq * Lq / 16), 256, 0, stream>>>(x32, emb, W, bias, ws, s_out);
    k_m<<<Bq * Dq * (Lq / RQ), 256, 0, stream>>>(x32, ws, m_out);
}

// Round 5
// 1043.284 us; speedup vs baseline: 1.2569x; 1.2569x over previous
//
#include <hip/hip_runtime.h>

#define Bq 2
#define Lq 1024
#define Dq 128
#define Vq 5
#define RQ 128   // l1 rows per k_m block

typedef __attribute__((ext_vector_type(4))) float float4v;

// ws layout (floats): [0,640) P1b  [640,1280) P2  [1280] x-dtype flag (int)
#define WS_FLAG_OFF 1280

// ---------------------------------------------------------------------------
// Kernel 0: x dtype insurance. int64 x -> odd int32 words all zero -> flag 0.
// int32 x -> odd words are random 0..4 -> flag nonzero w.p. 1 - 5^-1024.
// ---------------------------------------------------------------------------
__global__ void k_flag(const int* __restrict__ x32, int* __restrict__ flag) {
    __shared__ int red[256];
    const int t = threadIdx.x;
    int acc = 0;
    for (int k = t; k < 1024; k += 256)
        acc |= x32[2 * k + 1];
    red[t] = acc;
    __syncthreads();
    for (int s = 128; s > 0; s >>= 1) {
        if (t < s) red[t] |= red[t + s];
        __syncthreads();
    }
    if (t == 0) flag[0] = red[0];
}

__device__ __forceinline__ int x_at(const int* __restrict__ x32, int f, int idx) {
    return x32[f ? idx : 2 * idx];   // f!=0: int32; f==0: int64 low word
}

// ---------------------------------------------------------------------------
// Kernel 1: blocks [0,5)   -> P1b[v][e] = sum_d emb[v,d]*W[e,d] + bias[e]
//                             P2 [v][e] = sum_d emb[v,d]*W[e,D+d]
//           blocks [5,133) -> s gather (fp32): s[b,l,:] = emb[x[b,l],:]
// ---------------------------------------------------------------------------
__global__ void k_prep(const int* __restrict__ x32,
                       const float* __restrict__ emb,
                       const float* __restrict__ W,
                       const float* __restrict__ bias,
                       float* __restrict__ ws,
                       float* __restrict__ s_out) {
    const int bid = blockIdx.x;
    const int t   = threadIdx.x;
    if (bid < Vq) {
        const int v     = bid;
        const int which = t >> 7;     // 0 -> P1 (+bias), 1 -> P2
        const int e     = t & 127;
        float acc = which ? 0.0f : bias[e];
        const float* wrow = W + e * (2 * Dq) + which * Dq;
        const float* erow = emb + v * Dq;
        #pragma unroll 8
        for (int d = 0; d < Dq; ++d)
            acc += erow[d] * wrow[d];
        ws[which * (Vq * Dq) + v * Dq + e] = acc;
    } else {
        const int f    = ((const int*)ws)[WS_FLAG_OFF];
        const int sb   = bid - Vq;            // 0..127
        const int pair = t >> 4;              // 0..15
        const int dgrp = t & 15;              // 0..15
        const int bl   = sb * 16 + pair;      // flat (b,l), 0..2047
        const int v    = x_at(x32, f, bl);
        const float* src = emb + v * Dq + dgrp * 8;
        float*       dst = s_out + (size_t)bl * Dq + dgrp * 8;
        float4v a = *reinterpret_cast<const float4v*>(src);
        float4v b = *reinterpret_cast<const float4v*>(src + 4);
        *reinterpret_cast<float4v*>(dst)     = a;
        *reinterpret_cast<float4v*>(dst + 4) = b;
    }
}

// ---------------------------------------------------------------------------
// Kernel 2: m[b,e,l1,l2] = P1b[x[b,l1],e] + P2[x[b,l2],e], fp32 out.
// grid = B*D*(L/RQ) = 2048 blocks, 256 threads.
// R5 change: PLAIN stores (no nontemporal) — nt suspected of defeating L2
// write-combining of the two half-dense dwordx4 store instructions.
// ---------------------------------------------------------------------------
__global__ void __launch_bounds__(256) k_m(const int* __restrict__ x32,
                                           const float* __restrict__ ws,
                                           float* __restrict__ m_out) {
    constexpr int CH = Lq / RQ;            // 8 chunks
    const int bid   = blockIdx.x;
    const int chunk = bid % CH;
    const int tmp   = bid / CH;
    const int e     = tmp % Dq;
    const int b     = tmp / Dq;
    const int t     = threadIdx.x;
    const int r     = t >> 7;              // 0..1
    const int c     = t & 127;             // 0..127
    const int l1_0  = chunk * RQ;
    const int f     = ((const int*)ws)[WS_FLAG_OFF];

    // P columns for this e (broadcast loads, L2-hit)
    float p1c[Vq], p2c[Vq];
    #pragma unroll
    for (int v = 0; v < Vq; ++v) {
        p1c[v] = ws[v * Dq + e];
        p2c[v] = ws[Vq * Dq + v * Dq + e];
    }

    // per-thread c2[8] for its 8 l2 positions
    const int xbase = b * Lq;
    float c2[8];
    #pragma unroll
    for (int j = 0; j < 8; ++j) {
        const int v = x_at(x32, f, xbase + c * 8 + j);
        float p = p2c[4];
        p = (v == 3) ? p2c[3] : p;
        p = (v == 2) ? p2c[2] : p;
        p = (v == 1) ? p2c[1] : p;
        p = (v == 0) ? p2c[0] : p;
        c2[j] = p;
    }

    // c1 for this block's 128 l1 rows, staged in LDS
    __shared__ float c1s[RQ];
    if (t < RQ) {
        const int v = x_at(x32, f, xbase + l1_0 + t);
        float p = p1c[4];
        p = (v == 3) ? p1c[3] : p;
        p = (v == 2) ? p1c[2] : p;
        p = (v == 1) ? p1c[1] : p;
        p = (v == 0) ? p1c[0] : p;
        c1s[t] = p;
    }
    __syncthreads();

    float* out_base = m_out
        + ((size_t)(b * Dq + e) * Lq + l1_0) * Lq + c * 8;

    #pragma unroll 4
    for (int i = r; i < RQ; i += 2) {
        const float c1 = c1s[i];           // wave-uniform broadcast
        float4v o0, o1;
        #pragma unroll
        for (int j = 0; j < 4; ++j) o0[j] = c1 + c2[j];
        #pragma unroll
        for (int j = 0; j < 4; ++j) o1[j] = c1 + c2[4 + j];
        float* dst = out_base + (size_t)i * Lq;
        *reinterpret_cast<float4v*>(dst)     = o0;
        *reinterpret_cast<float4v*>(dst + 4) = o1;
    }
}

extern "C" void kernel_launch(void* const* d_in, const int* in_sizes, int n_in,
                              void* d_out, int out_size, void* d_ws, size_t ws_size,
                              hipStream_t stream) {
    const int*   x32  = (const int*)d_in[0];    // int32 (int64 auto-handled)
    const float* emb  = (const float*)d_in[1];
    const float* W    = (const float*)d_in[2];
    const float* bias = (const float*)d_in[3];
    float* out   = (float*)d_out;               // fp32 output buffer
    float* ws    = (float*)d_ws;
    float* s_out = out;
    float* m_out = out + (size_t)Bq * Lq * Dq;

    k_flag<<<1, 256, 0, stream>>>(x32, ((int*)ws) + WS_FLAG_OFF);
    k_prep<<<Vq + (Bq * Lq / 16), 256, 0, stream>>>(x32, emb, W, bias, ws, s_out);
    k_m<<<Bq * Dq * (Lq / RQ), 256, 0, stream>>>(x32, ws, m_out);
}